// Round 10
// baseline (1644.926 us; speedup 1.0000x reference)
//
#include <hip/hip_runtime.h>
#include <hip/hip_bf16.h>

// ---------------- problem constants ----------------
#define NB 400000     // n_bonds
#define NA 100000     // n_atoms
#define AFD 133       // atom feature dim
#define BFD 147       // bond feature dim
#define HID 300       // hidden
#define NP  320       // padded hidden
#define NT  98        // scan tiles: ceil(NA/1024)

typedef short short8 __attribute__((ext_vector_type(8)));
typedef float f32x4 __attribute__((ext_vector_type(4)));

__device__ __forceinline__ ushort f2b(float f) {
    union { float f; unsigned u; } v; v.f = f;
    unsigned r = v.u + 0x7fffu + ((v.u >> 16) & 1u);
    return (ushort)(r >> 16);
}
__device__ __forceinline__ float b2f(ushort u) {
    union { unsigned u; float f; } v; v.u = ((unsigned)u) << 16;
    return v.f;
}

// global_load_lds: per-lane global src (16B); LDS dest = wave-uniform base,
// HW places lane i at base + i*16.
#define GLDS(gp, lp) __builtin_amdgcn_global_load_lds( \
    (const __attribute__((address_space(1))) void*)(gp), \
    (__attribute__((address_space(3))) void*)(lp), 16, 0, 0)

// k-map: within each 32-k tile, granule g holds natural ks {8g..8g+7} on BOTH
// operands. Weights bank-swizzled: stored gp = g^((n>>1)&3).

// ---------------- merged weight/bias prep ----------------
__device__ __forceinline__ void pad_one(const float* __restrict__ W,
                                        ushort* __restrict__ Wp,
                                        int idx, int N, int K, int Kp) {
    int n = idx / Kp, k = idx - n * Kp;
    int t = k >> 5, kk = k & 31;
    int g = kk >> 3, s = kk & 7;
    int gp = g ^ ((n >> 1) & 3);
    ushort v = (n < N && k < K) ? f2b(W[n * K + k]) : (ushort)0;
    Wp[(size_t)t * 10240 + n * 32 + gp * 8 + s] = v;
}

__global__ void prep_w_k(const float* __restrict__ Wi, const float* __restrict__ Wh,
                         const float* __restrict__ Wo, const float* __restrict__ bh,
                         ushort* __restrict__ Wp0, ushort* __restrict__ Wp1,
                         ushort* __restrict__ Wp2, float* __restrict__ bhp) {
    int idx = blockIdx.x * 256 + threadIdx.x;
    const int n0 = NP * 192, n1 = NP * 320, n2 = NP * 448;
    if (idx < n0) { pad_one(Wi, Wp0, idx, HID, BFD, 192); return; }
    idx -= n0;
    if (idx < n1) { pad_one(Wh, Wp1, idx, HID, HID, 320); return; }
    idx -= n1;
    if (idx < n2) { pad_one(Wo, Wp2, idx, HID, AFD + HID, 448); return; }
    idx -= n2;
    if (idx < NP) bhp[idx] = (idx < HID) ? bh[idx] : 0.f;
}

// ---------------- CSR build: dest+count -> scan -> scatter ----------------
__global__ void dest_count_k(const int* __restrict__ b2a, const int* __restrict__ b2revb,
                             int* __restrict__ dest, int* __restrict__ cnt) {
    int b = blockIdx.x * 256 + threadIdx.x;
    if (b >= NB) return;
    int d = b2a[b2revb[b]];
    dest[b] = d;
    atomicAdd(&cnt[d], 1);
}

__global__ void scanA_k(const int* __restrict__ cnt, int* __restrict__ tsum) {
    __shared__ int sm[256];
    const int tid = threadIdx.x;
    int base = blockIdx.x * 1024 + tid * 4;
    int s = 0;
#pragma unroll
    for (int j = 0; j < 4; ++j) { int i = base + j; if (i < NA) s += cnt[i]; }
    sm[tid] = s; __syncthreads();
    for (int o = 128; o > 0; o >>= 1) {
        if (tid < o) sm[tid] += sm[tid + o];
        __syncthreads();
    }
    if (tid == 0) tsum[blockIdx.x] = sm[0];
}

__global__ void scanB_k(const int* __restrict__ tsum, int* __restrict__ toff,
                        int* __restrict__ rs) {
    if (threadIdx.x == 0) {
        int run = 0;
        for (int t = 0; t < NT; ++t) { toff[t] = run; run += tsum[t]; }
        rs[NA] = run;
    }
}

__global__ void scanC_k(const int* __restrict__ cnt, const int* __restrict__ toff,
                        int* __restrict__ rs) {
    __shared__ int sm[256];
    const int tid = threadIdx.x;
    int base = blockIdx.x * 1024 + tid * 4;
    int v[4]; int s = 0;
#pragma unroll
    for (int j = 0; j < 4; ++j) {
        v[j] = (base + j < NA) ? cnt[base + j] : 0;
        s += v[j];
    }
    sm[tid] = s; __syncthreads();
    for (int o = 1; o < 256; o <<= 1) {
        int x = (tid >= o) ? sm[tid - o] : 0;
        __syncthreads();
        sm[tid] += x;
        __syncthreads();
    }
    int acc = sm[tid] - s + toff[blockIdx.x];
#pragma unroll
    for (int j = 0; j < 4; ++j) {
        if (base + j < NA) rs[base + j] = acc;
        acc += v[j];
    }
}

__global__ void scatter_k(const int* __restrict__ dest, const int* __restrict__ rs,
                          int* __restrict__ cur, int* __restrict__ bl) {
    int b = blockIdx.x * 256 + threadIdx.x;
    if (b >= NB) return;
    int a = dest[b];
    int pos = rs[a] + atomicAdd(&cur[a], 1);
    bl[pos] = b;
}

// ---------------- edge GEMMs (hoisted VALU-staged A) ----------------
// MODE 0: Cb = relu(bf16(f_bonds) @ W^T + bias)          KP=192, LDS-transposed epi
// MODE 2: Cf = relu(bf16(concat(f_atoms,SHb)) @ W^T + b) KP=448, direct fp32 epi
template<int MODE>
__global__ __launch_bounds__(512) void gemm_k(
    const float* __restrict__ F1, const ushort* __restrict__ SHb,
    const ushort* __restrict__ W, const float* __restrict__ bias,
    ushort* __restrict__ Cb, float* __restrict__ Cf, int M)
{
    constexpr int KP = (MODE == 0) ? 192 : 448;
    constexpr int TILES = KP / 32;           // 6 / 14 -- even
    static_assert(KP % 64 == 0 && TILES % 2 == 0, "XOR swizzle needs 128B rows, even tiles");
    __shared__ __align__(16) char smem[(128 * KP + 2 * 10240) * 2];
    ushort (*Bs)[10240] = (ushort (*)[10240])(smem + 128 * KP * 2);

    const int tid = threadIdx.x;
    const int w = tid >> 6, lane = tid & 63;
    const int wr = w >> 2, wc = w & 3;
    const int g = lane >> 4, lr = lane & 15;
    const int m0 = blockIdx.x * 128;

    // hoisted A staging: thread (row, q) writes granule q (ks 8q..8q+7) per tile
    {
        const int row = tid >> 2, q = tid & 3;
        int grow = m0 + row;
        if (MODE == 2 && grow >= M) grow = M - 1;
        const int axw = (row & 7) << 4;
        char* abase = smem + (size_t)row * (KP * 2);
#pragma unroll
        for (int t = 0; t < TILES; ++t) {
            const int k0 = t * 32 + q * 8;
            ushort o[8];
            if (MODE == 0) {
                const float* src = F1 + (size_t)grow * BFD;
#pragma unroll
                for (int s = 0; s < 8; ++s)
                    o[s] = (k0 + s < BFD) ? f2b(src[k0 + s]) : (ushort)0;
            } else {
#pragma unroll
                for (int s = 0; s < 8; ++s) {
                    int k = k0 + s;
                    o[s] = (k < AFD) ? f2b(F1[(size_t)grow * AFD + k])
                                     : SHb[(size_t)grow * NP + (k - AFD)];
                }
            }
            ushort* dst = (ushort*)(abase + ((t * 64 + q * 16) ^ axw));
            *(ushort4*)dst       = make_ushort4(o[0], o[1], o[2], o[3]);
            *(ushort4*)(dst + 4) = make_ushort4(o[4], o[5], o[6], o[7]);
        }
    }

    auto stageB = [&](int t, int buf) {
        const ushort* wt = W + (size_t)t * 10240;
        ushort* bs = &Bs[buf][0];
        GLDS(wt + (size_t)w * 512 + lane * 8,        bs + w * 512);
        GLDS(wt + (size_t)(w + 8) * 512 + lane * 8,  bs + (w + 8) * 512);
        if (w < 4)
            GLDS(wt + (size_t)(w + 16) * 512 + lane * 8, bs + (w + 16) * 512);
    };

    f32x4 acc[4][5];
#pragma unroll
    for (int mi = 0; mi < 4; ++mi)
#pragma unroll
        for (int ni = 0; ni < 5; ++ni) acc[mi][ni] = (f32x4){0.f, 0.f, 0.f, 0.f};

    stageB(0, 0);
    __syncthreads();

    const int raxw = (lr & 7) << 4;
    const int bswz = (lr >> 1) & 3;
    for (int t = 0; t < TILES; ++t) {
        if (t + 1 < TILES) stageB(t + 1, (t + 1) & 1);
        const ushort* bs = &Bs[t & 1][0];
        short8 af[4];
#pragma unroll
        for (int mi = 0; mi < 4; ++mi) {
            const int r = wr * 64 + mi * 16 + lr;
            af[mi] = *(const short8*)(smem + (size_t)r * (KP * 2)
                                      + ((t * 64 + g * 16) ^ raxw));
        }
#pragma unroll
        for (int ni = 0; ni < 5; ++ni) {
            const int c = wc * 80 + ni * 16 + lr;
            short8 bf = *(const short8*)&bs[c * 32 + ((g ^ bswz) << 3)];
#pragma unroll
            for (int mi = 0; mi < 4; ++mi)
                acc[mi][ni] = __builtin_amdgcn_mfma_f32_16x16x32_bf16(af[mi], bf, acc[mi][ni], 0, 0, 0);
        }
        __syncthreads();
    }

    if (MODE == 0) {
        // LDS-transposed epilogue: 4 phases over wc; coalesced 8B stores
        float* EP = (float*)smem;   // 128 x 84 f32 = 43008 B (aliases As region)
        for (int ph = 0; ph < 4; ++ph) {
            __syncthreads();
            if (wc == ph) {
#pragma unroll
                for (int mi = 0; mi < 4; ++mi)
#pragma unroll
                    for (int ni = 0; ni < 5; ++ni) {
                        const int ec = ni * 16 + lr;
#pragma unroll
                        for (int r = 0; r < 4; ++r)
                            EP[(wr * 64 + mi * 16 + g * 4 + r) * 84 + ec] = acc[mi][ni][r];
                    }
            }
            __syncthreads();
            for (int it2 = tid; it2 < 2560; it2 += 512) {
                const int row = it2 / 20, cc = (it2 - row * 20) * 4;
                const int grow = m0 + row;
                const int col = ph * 80 + cc;
                float4 a = *(const float4*)&EP[row * 84 + cc];
                float4 bb = (col < HID) ? *(const float4*)&bias[col]
                                        : make_float4(0.f, 0.f, 0.f, 0.f);
                *(ushort4*)&Cb[(size_t)grow * NP + col] =
                    make_ushort4(f2b(fmaxf(a.x + bb.x, 0.f)), f2b(fmaxf(a.y + bb.y, 0.f)),
                                 f2b(fmaxf(a.z + bb.z, 0.f)), f2b(fmaxf(a.w + bb.w, 0.f)));
            }
        }
    } else {
#pragma unroll
        for (int ni = 0; ni < 5; ++ni) {
            const int col = wc * 80 + ni * 16 + lr;
            const float bv = (col < HID) ? bias[col] : 0.f;
#pragma unroll
            for (int mi = 0; mi < 4; ++mi) {
                const int row0 = m0 + wr * 64 + mi * 16 + g * 4;
#pragma unroll
                for (int r = 0; r < 4; ++r) {
                    const int row = row0 + r;
                    float v = fmaxf(acc[mi][ni][r] + bv, 0.f);
                    if (col < HID && row < M) Cf[(size_t)row * HID + col] = v;
                }
            }
        }
    }
}

// ---------------- dense GEMM: Y = Hb @ Wh^T (no bias/relu) ----------------
// A loaded DIRECTLY global->reg (lane-private fragments, software prefetch);
// B double-buffered via GLDS; LDS-transposed coalesced Y write epilogue.
__global__ __launch_bounds__(512) void gemm_h_k(
    const ushort* __restrict__ Hb, const ushort* __restrict__ W,
    ushort* __restrict__ Y)
{
    __shared__ __align__(16) char smem[43008];      // max(Bs dbuf 40960, EP 43008)
    ushort (*Bs)[10240] = (ushort (*)[10240])smem;
    const int tid = threadIdx.x;
    const int w = tid >> 6, lane = tid & 63;
    const int wr = w >> 2, wc = w & 3;
    const int g = lane >> 4, lr = lane & 15;
    const int m0 = blockIdx.x * 128;

    auto stageB = [&](int t, int buf) {
        const ushort* wt = W + (size_t)t * 10240;
        ushort* bs = &Bs[buf][0];
        GLDS(wt + (size_t)w * 512 + lane * 8,        bs + w * 512);
        GLDS(wt + (size_t)(w + 8) * 512 + lane * 8,  bs + (w + 8) * 512);
        if (w < 4)
            GLDS(wt + (size_t)(w + 16) * 512 + lane * 8, bs + (w + 16) * 512);
    };

    f32x4 acc[4][5];
#pragma unroll
    for (int mi = 0; mi < 4; ++mi)
#pragma unroll
        for (int ni = 0; ni < 5; ++ni) acc[mi][ni] = (f32x4){0.f, 0.f, 0.f, 0.f};

    const ushort* arow[4];
#pragma unroll
    for (int mi = 0; mi < 4; ++mi)
        arow[mi] = Hb + (size_t)(m0 + wr * 64 + mi * 16 + lr) * NP + g * 8;

    stageB(0, 0);
    short8 afc[4];
#pragma unroll
    for (int mi = 0; mi < 4; ++mi) afc[mi] = *(const short8*)arow[mi];
    __syncthreads();

    const int bswz = (lr >> 1) & 3;
    for (int t = 0; t < 10; ++t) {
        if (t < 9) stageB(t + 1, (t + 1) & 1);
        short8 afn[4];
        if (t < 9) {
#pragma unroll
            for (int mi = 0; mi < 4; ++mi)
                afn[mi] = *(const short8*)(arow[mi] + (t + 1) * 32);
        }
        const ushort* bs = &Bs[t & 1][0];
#pragma unroll
        for (int ni = 0; ni < 5; ++ni) {
            const int c = wc * 80 + ni * 16 + lr;
            short8 bf = *(const short8*)&bs[c * 32 + ((g ^ bswz) << 3)];
#pragma unroll
            for (int mi = 0; mi < 4; ++mi)
                acc[mi][ni] = __builtin_amdgcn_mfma_f32_16x16x32_bf16(afc[mi], bf, acc[mi][ni], 0, 0, 0);
        }
        __syncthreads();
        if (t < 9) {
#pragma unroll
            for (int mi = 0; mi < 4; ++mi) afc[mi] = afn[mi];
        }
    }

    // LDS-transposed epilogue: coalesced 8B Y stores
    float* EP = (float*)smem;   // 128 x 84 f32 (staging LDS is dead)
    for (int ph = 0; ph < 4; ++ph) {
        __syncthreads();
        if (wc == ph) {
#pragma unroll
            for (int mi = 0; mi < 4; ++mi)
#pragma unroll
                for (int ni = 0; ni < 5; ++ni) {
                    const int ec = ni * 16 + lr;
#pragma unroll
                    for (int r = 0; r < 4; ++r)
                        EP[(wr * 64 + mi * 16 + g * 4 + r) * 84 + ec] = acc[mi][ni][r];
                }
        }
        __syncthreads();
        for (int it2 = tid; it2 < 2560; it2 += 512) {
            const int row = it2 / 20, cc = (it2 - row * 20) * 4;
            const int col = ph * 80 + cc;
            float4 a = *(const float4*)&EP[row * 84 + cc];
            *(ushort4*)&Y[(size_t)(m0 + row) * NP + col] =
                make_ushort4(f2b(a.x), f2b(a.y), f2b(a.z), f2b(a.w));
        }
    }
}

// ---------------- SH = segsum(H) -> bf16 [NA][NP] (CSR gather) ----------------
__global__ void seg_sum_bf16_k(const ushort* __restrict__ H, const int* __restrict__ rs,
                               const int* __restrict__ bl, ushort* __restrict__ SH) {
    int idx = blockIdx.x * 256 + threadIdx.x;
    if (idx >= NA * 40) return;
    int a = idx / 40, c = (idx - a * 40) * 8;
    int s0 = rs[a], s1 = rs[a + 1];
    float acc[8] = {0.f, 0.f, 0.f, 0.f, 0.f, 0.f, 0.f, 0.f};
    for (int j = s0; j < s1; ++j) {
        const ushort* p = &H[(size_t)bl[j] * NP + c];
        ushort4 u0 = *(const ushort4*)p, u1 = *(const ushort4*)(p + 4);
        acc[0] += b2f(u0.x); acc[1] += b2f(u0.y);
        acc[2] += b2f(u0.z); acc[3] += b2f(u0.w);
        acc[4] += b2f(u1.x); acc[5] += b2f(u1.y);
        acc[6] += b2f(u1.z); acc[7] += b2f(u1.w);
    }
    ushort* dst = &SH[(size_t)a * NP + c];
    *(ushort4*)dst       = make_ushort4(f2b(acc[0]), f2b(acc[1]), f2b(acc[2]), f2b(acc[3]));
    *(ushort4*)(dst + 4) = make_ushort4(f2b(acc[4]), f2b(acc[5]), f2b(acc[6]), f2b(acc[7]));
}

// ------ update: Hb = relu(Hb + SY[b2a] - Y[b2revb] + bh), in-place ------
// OUTF: also write fp32 H_bonds output (cols < HID).
template<bool OUTF>
__global__ void update_k(ushort* __restrict__ Hb, const ushort* __restrict__ SY,
                         const ushort* __restrict__ Y,
                         const int* __restrict__ b2a, const int* __restrict__ b2revb,
                         const float* __restrict__ bhp, float* __restrict__ Hbonds) {
    int idx = blockIdx.x * 256 + threadIdx.x;
    if (idx >= NB * 40) return;
    int b = idx / 40, c = (idx - b * 40) * 8;
    int sa = b2a[b], rb = b2revb[b];
    ushort* hp = &Hb[(size_t)b * NP + c];
    const ushort* sp = &SY[(size_t)sa * NP + c];
    const ushort* yp = &Y[(size_t)rb * NP + c];
    ushort4 h0 = *(const ushort4*)hp,       h1 = *(const ushort4*)(hp + 4);
    ushort4 s0 = *(const ushort4*)sp,       s1 = *(const ushort4*)(sp + 4);
    ushort4 y0 = *(const ushort4*)yp,       y1 = *(const ushort4*)(yp + 4);
    float4 bl0 = *(const float4*)&bhp[c], bl1 = *(const float4*)&bhp[c + 4];
    float v[8];
    v[0] = fmaxf(b2f(h0.x) + b2f(s0.x) - b2f(y0.x) + bl0.x, 0.f);
    v[1] = fmaxf(b2f(h0.y) + b2f(s0.y) - b2f(y0.y) + bl0.y, 0.f);
    v[2] = fmaxf(b2f(h0.z) + b2f(s0.z) - b2f(y0.z) + bl0.z, 0.f);
    v[3] = fmaxf(b2f(h0.w) + b2f(s0.w) - b2f(y0.w) + bl0.w, 0.f);
    v[4] = fmaxf(b2f(h1.x) + b2f(s1.x) - b2f(y1.x) + bl1.x, 0.f);
    v[5] = fmaxf(b2f(h1.y) + b2f(s1.y) - b2f(y1.y) + bl1.y, 0.f);
    v[6] = fmaxf(b2f(h1.z) + b2f(s1.z) - b2f(y1.z) + bl1.z, 0.f);
    v[7] = fmaxf(b2f(h1.w) + b2f(s1.w) - b2f(y1.w) + bl1.w, 0.f);
    *(ushort4*)hp       = make_ushort4(f2b(v[0]), f2b(v[1]), f2b(v[2]), f2b(v[3]));
    *(ushort4*)(hp + 4) = make_ushort4(f2b(v[4]), f2b(v[5]), f2b(v[6]), f2b(v[7]));
    if (OUTF && c < HID) {
        float* op = &Hbonds[(size_t)b * HID + c];
        *(float4*)op = make_float4(v[0], v[1], v[2], v[3]);
        if (c + 4 < HID) *(float4*)(op + 4) = make_float4(v[4], v[5], v[6], v[7]);
    }
}

extern "C" void kernel_launch(void* const* d_in, const int* in_sizes, int n_in,
                              void* d_out, int out_size, void* d_ws, size_t ws_size,
                              hipStream_t stream) {
    const float* f_atoms = (const float*)d_in[0];
    const float* f_bonds = (const float*)d_in[1];
    const int*   b2a     = (const int*)d_in[2];
    const int*   b2revb  = (const int*)d_in[3];
    const float* Wi_w    = (const float*)d_in[4];
    const float* Wi_b    = (const float*)d_in[5];
    const float* Wh_w    = (const float*)d_in[6];
    const float* Wh_b    = (const float*)d_in[7];
    const float* Wo_w    = (const float*)d_in[8];
    const float* Wo_b    = (const float*)d_in[9];
    float* out = (float*)d_out;

    // workspace layout (~580 MB of 2.4 GB)
    char* ws = (char*)d_ws;
    ushort* Hb   = (ushort*)ws;            ws += (size_t)NB * NP * 2;   // 256 MB
    ushort* Y    = (ushort*)ws;            ws += (size_t)NB * NP * 2;   // 256 MB
    ushort* SY   = (ushort*)ws;            ws += (size_t)NA * NP * 2;   // 64 MB
    int*    dest = (int*)ws;               ws += (size_t)NB * 4;
    ushort* Wp0  = (ushort*)ws;            ws += (size_t)6  * 10240 * 2;
    ushort* Wp1  = (ushort*)ws;            ws += (size_t)10 * 10240 * 2;
    ushort* Wp2  = (ushort*)ws;            ws += (size_t)14 * 10240 * 2;
    float*  bhp  = (float*)ws;             ws += (size_t)NP * 4;
    int*    cnt  = (int*)ws;               ws += (size_t)NA * 4;   // cnt+cur adjacent:
    int*    cur  = (int*)ws;               ws += (size_t)NA * 4;   // single memset
    int*    rs   = (int*)ws;               ws += (size_t)(NA + 1) * 4;
    int*    bl   = (int*)ws;               ws += (size_t)NB * 4;
    int*    tsum = (int*)ws;               ws += 128 * 4;
    int*    toff = (int*)ws;               ws += 128 * 4;
    float* Hatoms = out;                            // [NA][HID]
    float* Hbonds = out + (size_t)NA * HID;         // [NB][HID]

    // prep (merged): weights+bias pad, memset cnt+cur, dest+count, scan, scatter
    const int prep_n = NP * 192 + NP * 320 + NP * 448 + NP;
    prep_w_k<<<(prep_n + 255) / 256, 256, 0, stream>>>(
        Wi_w, Wh_w, Wo_w, Wh_b, Wp0, Wp1, Wp2, bhp);
    hipMemsetAsync(cnt, 0, (size_t)2 * NA * 4, stream);
    dest_count_k<<<(NB + 255) / 256, 256, 0, stream>>>(b2a, b2revb, dest, cnt);
    scanA_k<<<NT, 256, 0, stream>>>(cnt, tsum);
    scanB_k<<<1, 64, 0, stream>>>(tsum, toff, rs);
    scanC_k<<<NT, 256, 0, stream>>>(cnt, toff, rs);
    scatter_k<<<(NB + 255) / 256, 256, 0, stream>>>(dest, rs, cur, bl);

    // Hb = relu(f_bonds @ Wi^T + bi)
    gemm_k<0><<<NB / 128, 512, 0, stream>>>(
        f_bonds, nullptr, Wp0, Wi_b, Hb, nullptr, NB);

    // 2 MP iterations: Y = Hb@Wh^T; SY = segsum(Y); Hb = relu(Hb + SY[b2a] - Y[b2revb] + bh)
    for (int it = 0; it < 2; ++it) {
        gemm_h_k<<<NB / 128, 512, 0, stream>>>(Hb, Wp1, Y);
        seg_sum_bf16_k<<<(NA * 40 + 255) / 256, 256, 0, stream>>>(Y, rs, bl, SY);
        if (it == 0)
            update_k<false><<<(NB * 40 + 255) / 256, 256, 0, stream>>>(
                Hb, SY, Y, b2a, b2revb, bhp, nullptr);
        else
            update_k<true><<<(NB * 40 + 255) / 256, 256, 0, stream>>>(
                Hb, SY, Y, b2a, b2revb, bhp, Hbonds);
    }

    // final segsum (bf16) + H_atoms = relu(concat(f_atoms, SY) @ Wo^T + bo)
    seg_sum_bf16_k<<<(NA * 40 + 255) / 256, 256, 0, stream>>>(Hb, rs, bl, SY);
    gemm_k<2><<<(NA + 127) / 128, 512, 0, stream>>>(
        f_atoms, SY, Wp2, Wo_b, nullptr, Hatoms, NA);
}

// Round 11
// 1527.028 us; speedup vs baseline: 1.0772x; 1.0772x over previous
//
#include <hip/hip_runtime.h>
#include <hip/hip_bf16.h>

// ---------------- problem constants ----------------
#define NB 400000     // n_bonds
#define NA 100000     // n_atoms
#define AFD 133       // atom feature dim
#define BFD 147       // bond feature dim
#define HID 300       // hidden
#define NP  320       // padded hidden
#define NT  98        // scan tiles: ceil(NA/1024)

typedef short short8 __attribute__((ext_vector_type(8)));
typedef float f32x4 __attribute__((ext_vector_type(4)));

__device__ __forceinline__ ushort f2b(float f) {
    union { float f; unsigned u; } v; v.f = f;
    unsigned r = v.u + 0x7fffu + ((v.u >> 16) & 1u);
    return (ushort)(r >> 16);
}
__device__ __forceinline__ float b2f(ushort u) {
    union { unsigned u; float f; } v; v.u = ((unsigned)u) << 16;
    return v.f;
}

// global_load_lds: per-lane global src (16B); LDS dest = wave-uniform base,
// HW places lane i at base + i*16.
#define GLDS(gp, lp) __builtin_amdgcn_global_load_lds( \
    (const __attribute__((address_space(1))) void*)(gp), \
    (__attribute__((address_space(3))) void*)(lp), 16, 0, 0)

// k-map: within each 32-k tile, granule g holds natural ks {8g..8g+7} on BOTH
// operands. Weights bank-swizzled: stored gp = g^((n>>1)&3).
// Lessons locked in (R5/R7/R8/R10): random row-gathers live in high-occupancy
// elementwise kernels, never GEMM staging; C-writes must be >=8B coalesced
// (LDS-transpose epilogue); A-operand is shared across the 4 wc-waves -> stage
// via LDS broadcast, not per-lane registers.

// ---------------- merged weight/bias prep ----------------
__device__ __forceinline__ void pad_one(const float* __restrict__ W,
                                        ushort* __restrict__ Wp,
                                        int idx, int N, int K, int Kp) {
    int n = idx / Kp, k = idx - n * Kp;
    int t = k >> 5, kk = k & 31;
    int g = kk >> 3, s = kk & 7;
    int gp = g ^ ((n >> 1) & 3);
    ushort v = (n < N && k < K) ? f2b(W[n * K + k]) : (ushort)0;
    Wp[(size_t)t * 10240 + n * 32 + gp * 8 + s] = v;
}

__global__ void prep_w_k(const float* __restrict__ Wi, const float* __restrict__ Wh,
                         const float* __restrict__ Wo, const float* __restrict__ bh,
                         ushort* __restrict__ Wp0, ushort* __restrict__ Wp1,
                         ushort* __restrict__ Wp2, float* __restrict__ bhp) {
    int idx = blockIdx.x * 256 + threadIdx.x;
    const int n0 = NP * 192, n1 = NP * 320, n2 = NP * 448;
    if (idx < n0) { pad_one(Wi, Wp0, idx, HID, BFD, 192); return; }
    idx -= n0;
    if (idx < n1) { pad_one(Wh, Wp1, idx, HID, HID, 320); return; }
    idx -= n1;
    if (idx < n2) { pad_one(Wo, Wp2, idx, HID, AFD + HID, 448); return; }
    idx -= n2;
    if (idx < NP) bhp[idx] = (idx < HID) ? bh[idx] : 0.f;
}

// ---------------- CSR build: dest+count -> scan -> scatter ----------------
__global__ void dest_count_k(const int* __restrict__ b2a, const int* __restrict__ b2revb,
                             int* __restrict__ dest, int* __restrict__ cnt) {
    int b = blockIdx.x * 256 + threadIdx.x;
    if (b >= NB) return;
    int d = b2a[b2revb[b]];
    dest[b] = d;
    atomicAdd(&cnt[d], 1);
}

__global__ void scanA_k(const int* __restrict__ cnt, int* __restrict__ tsum) {
    __shared__ int sm[256];
    const int tid = threadIdx.x;
    int base = blockIdx.x * 1024 + tid * 4;
    int s = 0;
#pragma unroll
    for (int j = 0; j < 4; ++j) { int i = base + j; if (i < NA) s += cnt[i]; }
    sm[tid] = s; __syncthreads();
    for (int o = 128; o > 0; o >>= 1) {
        if (tid < o) sm[tid] += sm[tid + o];
        __syncthreads();
    }
    if (tid == 0) tsum[blockIdx.x] = sm[0];
}

__global__ void scanB_k(const int* __restrict__ tsum, int* __restrict__ toff,
                        int* __restrict__ rs) {
    if (threadIdx.x == 0) {
        int run = 0;
        for (int t = 0; t < NT; ++t) { toff[t] = run; run += tsum[t]; }
        rs[NA] = run;
    }
}

__global__ void scanC_k(const int* __restrict__ cnt, const int* __restrict__ toff,
                        int* __restrict__ rs) {
    __shared__ int sm[256];
    const int tid = threadIdx.x;
    int base = blockIdx.x * 1024 + tid * 4;
    int v[4]; int s = 0;
#pragma unroll
    for (int j = 0; j < 4; ++j) {
        v[j] = (base + j < NA) ? cnt[base + j] : 0;
        s += v[j];
    }
    sm[tid] = s; __syncthreads();
    for (int o = 1; o < 256; o <<= 1) {
        int x = (tid >= o) ? sm[tid - o] : 0;
        __syncthreads();
        sm[tid] += x;
        __syncthreads();
    }
    int acc = sm[tid] - s + toff[blockIdx.x];
#pragma unroll
    for (int j = 0; j < 4; ++j) {
        if (base + j < NA) rs[base + j] = acc;
        acc += v[j];
    }
}

__global__ void scatter_k(const int* __restrict__ dest, const int* __restrict__ rs,
                          int* __restrict__ cur, int* __restrict__ bl) {
    int b = blockIdx.x * 256 + threadIdx.x;
    if (b >= NB) return;
    int a = dest[b];
    int pos = rs[a] + atomicAdd(&cur[a], 1);
    bl[pos] = b;
}

// ---------------- edge GEMMs (hoisted VALU-staged A) ----------------
// MODE 0: Cb = relu(bf16(f_bonds) @ W^T + bias)          KP=192, LDS-transposed epi
// MODE 2: Cf = relu(bf16(concat(f_atoms,SHb)) @ W^T + b) KP=448, direct fp32 epi
template<int MODE>
__global__ __launch_bounds__(512) void gemm_k(
    const float* __restrict__ F1, const ushort* __restrict__ SHb,
    const ushort* __restrict__ W, const float* __restrict__ bias,
    ushort* __restrict__ Cb, float* __restrict__ Cf, int M)
{
    constexpr int KP = (MODE == 0) ? 192 : 448;
    constexpr int TILES = KP / 32;           // 6 / 14 -- even
    static_assert(KP % 64 == 0 && TILES % 2 == 0, "XOR swizzle needs 128B rows, even tiles");
    __shared__ __align__(16) char smem[(128 * KP + 2 * 10240) * 2];
    ushort (*Bs)[10240] = (ushort (*)[10240])(smem + 128 * KP * 2);

    const int tid = threadIdx.x;
    const int w = tid >> 6, lane = tid & 63;
    const int wr = w >> 2, wc = w & 3;
    const int g = lane >> 4, lr = lane & 15;
    const int m0 = blockIdx.x * 128;

    // hoisted A staging: thread (row, q) writes granule q (ks 8q..8q+7) per tile
    {
        const int row = tid >> 2, q = tid & 3;
        int grow = m0 + row;
        if (MODE == 2 && grow >= M) grow = M - 1;
        const int axw = (row & 7) << 4;
        char* abase = smem + (size_t)row * (KP * 2);
#pragma unroll
        for (int t = 0; t < TILES; ++t) {
            const int k0 = t * 32 + q * 8;
            ushort o[8];
            if (MODE == 0) {
                const float* src = F1 + (size_t)grow * BFD;
#pragma unroll
                for (int s = 0; s < 8; ++s)
                    o[s] = (k0 + s < BFD) ? f2b(src[k0 + s]) : (ushort)0;
            } else {
#pragma unroll
                for (int s = 0; s < 8; ++s) {
                    int k = k0 + s;
                    o[s] = (k < AFD) ? f2b(F1[(size_t)grow * AFD + k])
                                     : SHb[(size_t)grow * NP + (k - AFD)];
                }
            }
            ushort* dst = (ushort*)(abase + ((t * 64 + q * 16) ^ axw));
            *(ushort4*)dst       = make_ushort4(o[0], o[1], o[2], o[3]);
            *(ushort4*)(dst + 4) = make_ushort4(o[4], o[5], o[6], o[7]);
        }
    }

    auto stageB = [&](int t, int buf) {
        const ushort* wt = W + (size_t)t * 10240;
        ushort* bs = &Bs[buf][0];
        GLDS(wt + (size_t)w * 512 + lane * 8,        bs + w * 512);
        GLDS(wt + (size_t)(w + 8) * 512 + lane * 8,  bs + (w + 8) * 512);
        if (w < 4)
            GLDS(wt + (size_t)(w + 16) * 512 + lane * 8, bs + (w + 16) * 512);
    };

    f32x4 acc[4][5];
#pragma unroll
    for (int mi = 0; mi < 4; ++mi)
#pragma unroll
        for (int ni = 0; ni < 5; ++ni) acc[mi][ni] = (f32x4){0.f, 0.f, 0.f, 0.f};

    stageB(0, 0);
    __syncthreads();

    const int raxw = (lr & 7) << 4;
    const int bswz = (lr >> 1) & 3;
    for (int t = 0; t < TILES; ++t) {
        if (t + 1 < TILES) stageB(t + 1, (t + 1) & 1);
        const ushort* bs = &Bs[t & 1][0];
        short8 af[4];
#pragma unroll
        for (int mi = 0; mi < 4; ++mi) {
            const int r = wr * 64 + mi * 16 + lr;
            af[mi] = *(const short8*)(smem + (size_t)r * (KP * 2)
                                      + ((t * 64 + g * 16) ^ raxw));
        }
#pragma unroll
        for (int ni = 0; ni < 5; ++ni) {
            const int c = wc * 80 + ni * 16 + lr;
            short8 bf = *(const short8*)&bs[c * 32 + ((g ^ bswz) << 3)];
#pragma unroll
            for (int mi = 0; mi < 4; ++mi)
                acc[mi][ni] = __builtin_amdgcn_mfma_f32_16x16x32_bf16(af[mi], bf, acc[mi][ni], 0, 0, 0);
        }
        __syncthreads();
    }

    if (MODE == 0) {
        // LDS-transposed epilogue: 4 phases over wc; coalesced 8B stores
        float* EP = (float*)smem;   // 128 x 84 f32 = 43008 B (aliases As region)
        for (int ph = 0; ph < 4; ++ph) {
            __syncthreads();
            if (wc == ph) {
#pragma unroll
                for (int mi = 0; mi < 4; ++mi)
#pragma unroll
                    for (int ni = 0; ni < 5; ++ni) {
                        const int ec = ni * 16 + lr;
#pragma unroll
                        for (int r = 0; r < 4; ++r)
                            EP[(wr * 64 + mi * 16 + g * 4 + r) * 84 + ec] = acc[mi][ni][r];
                    }
            }
            __syncthreads();
            for (int it2 = tid; it2 < 2560; it2 += 512) {
                const int row = it2 / 20, cc = (it2 - row * 20) * 4;
                const int grow = m0 + row;
                const int col = ph * 80 + cc;
                float4 a = *(const float4*)&EP[row * 84 + cc];
                float4 bb = (col < HID) ? *(const float4*)&bias[col]
                                        : make_float4(0.f, 0.f, 0.f, 0.f);
                *(ushort4*)&Cb[(size_t)grow * NP + col] =
                    make_ushort4(f2b(fmaxf(a.x + bb.x, 0.f)), f2b(fmaxf(a.y + bb.y, 0.f)),
                                 f2b(fmaxf(a.z + bb.z, 0.f)), f2b(fmaxf(a.w + bb.w, 0.f)));
            }
        }
    } else {
#pragma unroll
        for (int ni = 0; ni < 5; ++ni) {
            const int col = wc * 80 + ni * 16 + lr;
            const float bv = (col < HID) ? bias[col] : 0.f;
#pragma unroll
            for (int mi = 0; mi < 4; ++mi) {
                const int row0 = m0 + wr * 64 + mi * 16 + g * 4;
#pragma unroll
                for (int r = 0; r < 4; ++r) {
                    const int row = row0 + r;
                    float v = fmaxf(acc[mi][ni][r] + bv, 0.f);
                    if (col < HID && row < M) Cf[(size_t)row * HID + col] = v;
                }
            }
        }
    }
}

// ---------------- dense GEMM: Y = Hb @ Wh^T (no bias/relu) ----------------
// Linear GLDS A staging (LDS broadcast across wc-waves); LDS-transposed
// coalesced Y write epilogue.  [R9 version — best known]
__global__ __launch_bounds__(512) void gemm_h_k(
    const ushort* __restrict__ Hb, const ushort* __restrict__ W,
    ushort* __restrict__ Y)
{
    __shared__ __align__(16) char smem[57344];
    ushort (*As)[4][128][8] = (ushort (*)[4][128][8])smem;          // 16384 B
    ushort (*Bs)[10240] = (ushort (*)[10240])(smem + 16384);        // 40960 B
    const int tid = threadIdx.x;
    const int w = tid >> 6, lane = tid & 63;
    const int wr = w >> 2, wc = w & 3;
    const int g = lane >> 4, lr = lane & 15;
    const int m0 = blockIdx.x * 128;

    const int q = w >> 1, r0 = (w & 1) * 64;
    const ushort* aglob = Hb + (size_t)(m0 + r0 + lane) * NP + q * 8;

    f32x4 acc[4][5];
#pragma unroll
    for (int mi = 0; mi < 4; ++mi)
#pragma unroll
        for (int ni = 0; ni < 5; ++ni) acc[mi][ni] = (f32x4){0.f, 0.f, 0.f, 0.f};

    auto stageA = [&](int t, int buf) { GLDS(aglob + t * 32, &As[buf][q][r0][0]); };
    auto stageB = [&](int t, int buf) {
        const ushort* wt = W + (size_t)t * 10240;
        ushort* bs = &Bs[buf][0];
        GLDS(wt + (size_t)w * 512 + lane * 8,        bs + w * 512);
        GLDS(wt + (size_t)(w + 8) * 512 + lane * 8,  bs + (w + 8) * 512);
        if (w < 4)
            GLDS(wt + (size_t)(w + 16) * 512 + lane * 8, bs + (w + 16) * 512);
    };

    stageA(0, 0); stageB(0, 0);
    __syncthreads();

    const int bswz = (lr >> 1) & 3;
    for (int t = 0; t < 10; ++t) {
        if (t < 9) { stageA(t + 1, (t + 1) & 1); stageB(t + 1, (t + 1) & 1); }
        const int buf = t & 1;
        short8 af[4];
#pragma unroll
        for (int mi = 0; mi < 4; ++mi)
            af[mi] = *(const short8*)&As[buf][g][wr * 64 + mi * 16 + lr][0];
#pragma unroll
        for (int ni = 0; ni < 5; ++ni) {
            const int c = wc * 80 + ni * 16 + lr;
            short8 bf = *(const short8*)&Bs[buf][c * 32 + ((g ^ bswz) << 3)];
#pragma unroll
            for (int mi = 0; mi < 4; ++mi)
                acc[mi][ni] = __builtin_amdgcn_mfma_f32_16x16x32_bf16(af[mi], bf, acc[mi][ni], 0, 0, 0);
        }
        __syncthreads();
    }

    // LDS-transposed epilogue: coalesced 8B Y stores
    float* EP = (float*)smem;   // 128 x 84 f32 (staging LDS is dead)
    for (int ph = 0; ph < 4; ++ph) {
        __syncthreads();
        if (wc == ph) {
#pragma unroll
            for (int mi = 0; mi < 4; ++mi)
#pragma unroll
                for (int ni = 0; ni < 5; ++ni) {
                    const int ec = ni * 16 + lr;
#pragma unroll
                    for (int r = 0; r < 4; ++r)
                        EP[(wr * 64 + mi * 16 + g * 4 + r) * 84 + ec] = acc[mi][ni][r];
                }
        }
        __syncthreads();
        for (int it2 = tid; it2 < 2560; it2 += 512) {
            const int row = it2 / 20, cc = (it2 - row * 20) * 4;
            const int col = ph * 80 + cc;
            float4 a = *(const float4*)&EP[row * 84 + cc];
            *(ushort4*)&Y[(size_t)(m0 + row) * NP + col] =
                make_ushort4(f2b(a.x), f2b(a.y), f2b(a.z), f2b(a.w));
        }
    }
}

// ---------------- SH = segsum(H) -> bf16 [NA][NP] (CSR gather) ----------------
__global__ void seg_sum_bf16_k(const ushort* __restrict__ H, const int* __restrict__ rs,
                               const int* __restrict__ bl, ushort* __restrict__ SH) {
    int idx = blockIdx.x * 256 + threadIdx.x;
    if (idx >= NA * 40) return;
    int a = idx / 40, c = (idx - a * 40) * 8;
    int s0 = rs[a], s1 = rs[a + 1];
    float acc[8] = {0.f, 0.f, 0.f, 0.f, 0.f, 0.f, 0.f, 0.f};
    for (int j = s0; j < s1; ++j) {
        const ushort* p = &H[(size_t)bl[j] * NP + c];
        ushort4 u0 = *(const ushort4*)p, u1 = *(const ushort4*)(p + 4);
        acc[0] += b2f(u0.x); acc[1] += b2f(u0.y);
        acc[2] += b2f(u0.z); acc[3] += b2f(u0.w);
        acc[4] += b2f(u1.x); acc[5] += b2f(u1.y);
        acc[6] += b2f(u1.z); acc[7] += b2f(u1.w);
    }
    ushort* dst = &SH[(size_t)a * NP + c];
    *(ushort4*)dst       = make_ushort4(f2b(acc[0]), f2b(acc[1]), f2b(acc[2]), f2b(acc[3]));
    *(ushort4*)(dst + 4) = make_ushort4(f2b(acc[4]), f2b(acc[5]), f2b(acc[6]), f2b(acc[7]));
}

// ------ update: Hb = relu(Hb + SY[b2a] - Y[b2revb] + bh), in-place ------
// OUTF: also write fp32 H_bonds output (cols < HID).
template<bool OUTF>
__global__ void update_k(ushort* __restrict__ Hb, const ushort* __restrict__ SY,
                         const ushort* __restrict__ Y,
                         const int* __restrict__ b2a, const int* __restrict__ b2revb,
                         const float* __restrict__ bhp, float* __restrict__ Hbonds) {
    int idx = blockIdx.x * 256 + threadIdx.x;
    if (idx >= NB * 40) return;
    int b = idx / 40, c = (idx - b * 40) * 8;
    int sa = b2a[b], rb = b2revb[b];
    ushort* hp = &Hb[(size_t)b * NP + c];
    const ushort* sp = &SY[(size_t)sa * NP + c];
    const ushort* yp = &Y[(size_t)rb * NP + c];
    ushort4 h0 = *(const ushort4*)hp,       h1 = *(const ushort4*)(hp + 4);
    ushort4 s0 = *(const ushort4*)sp,       s1 = *(const ushort4*)(sp + 4);
    ushort4 y0 = *(const ushort4*)yp,       y1 = *(const ushort4*)(yp + 4);
    float4 bl0 = *(const float4*)&bhp[c], bl1 = *(const float4*)&bhp[c + 4];
    float v[8];
    v[0] = fmaxf(b2f(h0.x) + b2f(s0.x) - b2f(y0.x) + bl0.x, 0.f);
    v[1] = fmaxf(b2f(h0.y) + b2f(s0.y) - b2f(y0.y) + bl0.y, 0.f);
    v[2] = fmaxf(b2f(h0.z) + b2f(s0.z) - b2f(y0.z) + bl0.z, 0.f);
    v[3] = fmaxf(b2f(h0.w) + b2f(s0.w) - b2f(y0.w) + bl0.w, 0.f);
    v[4] = fmaxf(b2f(h1.x) + b2f(s1.x) - b2f(y1.x) + bl1.x, 0.f);
    v[5] = fmaxf(b2f(h1.y) + b2f(s1.y) - b2f(y1.y) + bl1.y, 0.f);
    v[6] = fmaxf(b2f(h1.z) + b2f(s1.z) - b2f(y1.z) + bl1.z, 0.f);
    v[7] = fmaxf(b2f(h1.w) + b2f(s1.w) - b2f(y1.w) + bl1.w, 0.f);
    *(ushort4*)hp       = make_ushort4(f2b(v[0]), f2b(v[1]), f2b(v[2]), f2b(v[3]));
    *(ushort4*)(hp + 4) = make_ushort4(f2b(v[4]), f2b(v[5]), f2b(v[6]), f2b(v[7]));
    if (OUTF && c < HID) {
        float* op = &Hbonds[(size_t)b * HID + c];
        *(float4*)op = make_float4(v[0], v[1], v[2], v[3]);
        if (c + 4 < HID) *(float4*)(op + 4) = make_float4(v[4], v[5], v[6], v[7]);
    }
}

extern "C" void kernel_launch(void* const* d_in, const int* in_sizes, int n_in,
                              void* d_out, int out_size, void* d_ws, size_t ws_size,
                              hipStream_t stream) {
    const float* f_atoms = (const float*)d_in[0];
    const float* f_bonds = (const float*)d_in[1];
    const int*   b2a     = (const int*)d_in[2];
    const int*   b2revb  = (const int*)d_in[3];
    const float* Wi_w    = (const float*)d_in[4];
    const float* Wi_b    = (const float*)d_in[5];
    const float* Wh_w    = (const float*)d_in[6];
    const float* Wh_b    = (const float*)d_in[7];
    const float* Wo_w    = (const float*)d_in[8];
    const float* Wo_b    = (const float*)d_in[9];
    float* out = (float*)d_out;

    // workspace layout (~580 MB of 2.4 GB)
    char* ws = (char*)d_ws;
    ushort* Hb   = (ushort*)ws;            ws += (size_t)NB * NP * 2;   // 256 MB
    ushort* Y    = (ushort*)ws;            ws += (size_t)NB * NP * 2;   // 256 MB
    ushort* SY   = (ushort*)ws;            ws += (size_t)NA * NP * 2;   // 64 MB
    int*    dest = (int*)ws;               ws += (size_t)NB * 4;
    ushort* Wp0  = (ushort*)ws;            ws += (size_t)6  * 10240 * 2;
    ushort* Wp1  = (ushort*)ws;            ws += (size_t)10 * 10240 * 2;
    ushort* Wp2  = (ushort*)ws;            ws += (size_t)14 * 10240 * 2;
    float*  bhp  = (float*)ws;             ws += (size_t)NP * 4;
    int*    cnt  = (int*)ws;               ws += (size_t)NA * 4;   // cnt+cur adjacent:
    int*    cur  = (int*)ws;               ws += (size_t)NA * 4;   // single memset
    int*    rs   = (int*)ws;               ws += (size_t)(NA + 1) * 4;
    int*    bl   = (int*)ws;               ws += (size_t)NB * 4;
    int*    tsum = (int*)ws;               ws += 128 * 4;
    int*    toff = (int*)ws;               ws += 128 * 4;
    float* Hatoms = out;                            // [NA][HID]
    float* Hbonds = out + (size_t)NA * HID;         // [NB][HID]

    // prep (merged): weights+bias pad, memset cnt+cur, dest+count, scan, scatter
    const int prep_n = NP * 192 + NP * 320 + NP * 448 + NP;
    prep_w_k<<<(prep_n + 255) / 256, 256, 0, stream>>>(
        Wi_w, Wh_w, Wo_w, Wh_b, Wp0, Wp1, Wp2, bhp);
    hipMemsetAsync(cnt, 0, (size_t)2 * NA * 4, stream);
    dest_count_k<<<(NB + 255) / 256, 256, 0, stream>>>(b2a, b2revb, dest, cnt);
    scanA_k<<<NT, 256, 0, stream>>>(cnt, tsum);
    scanB_k<<<1, 64, 0, stream>>>(tsum, toff, rs);
    scanC_k<<<NT, 256, 0, stream>>>(cnt, toff, rs);
    scatter_k<<<(NB + 255) / 256, 256, 0, stream>>>(dest, rs, cur, bl);

    // Hb = relu(f_bonds @ Wi^T + bi)
    gemm_k<0><<<NB / 128, 512, 0, stream>>>(
        f_bonds, nullptr, Wp0, Wi_b, Hb, nullptr, NB);

    // 2 MP iterations: Y = Hb@Wh^T; SY = segsum(Y); Hb = relu(Hb + SY[b2a] - Y[b2revb] + bh)
    for (int it = 0; it < 2; ++it) {
        gemm_h_k<<<NB / 128, 512, 0, stream>>>(Hb, Wp1, Y);
        seg_sum_bf16_k<<<(NA * 40 + 255) / 256, 256, 0, stream>>>(Y, rs, bl, SY);
        if (it == 0)
            update_k<false><<<(NB * 40 + 255) / 256, 256, 0, stream>>>(
                Hb, SY, Y, b2a, b2revb, bhp, nullptr);
        else
            update_k<true><<<(NB * 40 + 255) / 256, 256, 0, stream>>>(
                Hb, SY, Y, b2a, b2revb, bhp, Hbonds);
    }

    // final segsum (bf16) + H_atoms = relu(concat(f_atoms, SY) @ Wo^T + bo)
    seg_sum_bf16_k<<<(NA * 40 + 255) / 256, 256, 0, stream>>>(Hb, rs, bl, SY);
    gemm_k<2><<<(NA + 127) / 128, 512, 0, stream>>>(
        f_atoms, SY, Wp2, Wo_b, nullptr, Hatoms, NA);
}